// Round 1
// 226.487 us; speedup vs baseline: 1.0065x; 1.0065x over previous
//
#include <hip/hip_runtime.h>
#include <hip/hip_bf16.h>

// Flash-attention (causal, GQA) B=4, S=1024, HQ=32, HK=8, D=128, fp32 io.
// R4: 32x32x16 MFMAs, S^T orientation (D = K·Q^T), kappa-permuted K slots so
// P exits softmax already in PV A-operand layout (no LDS round-trip, no Ps).
// 256 thr / 4 waves, wave = 32 q rows, BQ=128, (256,2): 256 VGPR budget.
// R5: causal load-balance. Old grid (1024 blocks, one q-tile each) had
// work 2..16 tiles/block AND the same-CU cohort {bx,bx+256,..} shares qt
// (qt=bx&7, XCD round-robin) -> CUs serving qt=7 did 64 tile-iters while
// qt=0 CUs did 8 (rocprof: Occupancy 12%, MfmaUtil 10% = tail drain).
// Now each block runs the PAIR (p, 7-p) sequentially: 2(p+1)+2(8-p) = 18
// iters for EVERY block; phase B reverses wave->row (wv=3-wave) so every
// wave is causal-active exactly 17 tiles. 512 equal blocks = 2/CU, no tail.
// Prefetch chain carries across the phase boundary (same b,hk => kvbase).
//
// Layout facts used (m74/m101-verified): 32x32 C/D: col=lane&31,
// row=(reg&3)+8*(reg>>2)+4*(lane>>5). A: m=lane&31, k=(lane>>5)*8+j.
// B: n=lane&31, k=(lane>>5)*8+j.
// kappa(mu): slot mu holds key 16*(mu_s>>1) + 8*mu_h + (mu_s&1)*4 + mu_r
// (mu = r + 4h + 8s) => P regs [8c..8c+7] are exactly PV A-frag elements.

typedef __bf16 v8bf __attribute__((ext_vector_type(8)));
typedef __bf16 v4bf __attribute__((ext_vector_type(4)));
typedef float  v16f __attribute__((ext_vector_type(16)));

#define NB  4
#define NS  1024
#define NHQ 32
#define NHK 8
#define ND  128
#define BQ  128
#define BK  64
#define KP  136

#define KOFF(r) (16*((r)>>3) + ((((r)>>2)&1)*4) + ((r)&3))

__global__ __launch_bounds__(256, 2)
void fattn(const float* __restrict__ qg, const float* __restrict__ kg,
           const float* __restrict__ vg, float* __restrict__ og)
{
  __shared__ __align__(16) __bf16 Ks[BK * KP];   // 17408 B, kappa-permuted rows
  __shared__ __align__(16) __bf16 Vt[ND * BK];   // 16384 B, R2 chunk swizzle
  __shared__ __align__(16) float  alq[4 * 32];   // per-wave alpha / inv-l bcast

  const int tid  = threadIdx.x;
  const int lane = tid & 63;
  const int wave = tid >> 6;
  const int half = lane >> 5;
  const int l31  = lane & 31;

  const int bx = blockIdx.x;
  const int p  = bx & 3;                 // q-tile pair id: tiles (p, 7-p)
  const int h  = (bx >> 2) & (NHQ - 1);
  const int b  = bx >> 7;
  const int hk = h >> 2;

  const float scale = 0.08838834764831845f;  // 1/sqrt(128)
  const size_t kvbase = (size_t)(b * NS) * (NHK * ND) + (size_t)hk * ND;

  // staging assignments
  const int rbase = tid >> 5;            // K: rows rbase + 8i, i=0..7
  const int kd4   = (tid & 31) << 2;     // K: d offset (float4)
  const int vd    = tid & 127;           // V: one d column
  const int vkb   = (tid >> 7) * 32;     // V: 32 keys
  const int vgb   = (tid >> 7) * 4;      // V: granule base (granule = 8 keys)

  float4 pk[8];
  float  pv[32];
  auto prefetch = [&](int kn) {
    #pragma unroll
    for (int i = 0; i < 8; ++i)
      pk[i] = *(const float4*)(kg + kvbase + (size_t)(kn + rbase + 8 * i) * (NHK * ND) + kd4);
    const float* vp = vg + kvbase + (size_t)(kn + vkb) * (NHK * ND) + vd;
    #pragma unroll
    for (int kk = 0; kk < 32; ++kk)
      pv[kk] = vp[(size_t)kk * (NHK * ND)];
  };

  prefetch(0);

  for (int ph = 0; ph < 2; ++ph) {
    const int qt = ph ? (7 - p) : p;
    const int wv = ph ? (3 - wave) : wave;   // reverse rows in phase B: per-wave
    const int q0 = qt * BQ;                  // causal-active = 17 tiles for all
    const int wqb = q0 + wv * 32;
    const int qglob = wqb + l31;             // this lane's q row (S^T col, accO m)
    const int ntiles = 2 * (qt + 1);

    // --- Q fragments (B-operand: n=q=l31, k=d=dM*16+half*8+j), scale folded ---
    v8bf qf[8];
    {
      const float* qp = qg + ((size_t)((b * NS + qglob) * NHQ + h)) * ND + half * 8;
      #pragma unroll
      for (int dM = 0; dM < 8; ++dM) {
        float4 f0 = *(const float4*)(qp + dM * 16);
        float4 f1 = *(const float4*)(qp + dM * 16 + 4);
        v8bf t;
        t[0]=(__bf16)(f0.x*scale); t[1]=(__bf16)(f0.y*scale);
        t[2]=(__bf16)(f0.z*scale); t[3]=(__bf16)(f0.w*scale);
        t[4]=(__bf16)(f1.x*scale); t[5]=(__bf16)(f1.y*scale);
        t[6]=(__bf16)(f1.z*scale); t[7]=(__bf16)(f1.w*scale);
        qf[dM] = t;
      }
    }

    v16f accO[4];
    #pragma unroll
    for (int dt = 0; dt < 4; ++dt)
      #pragma unroll
      for (int e = 0; e < 16; ++e) accO[dt][e] = 0.f;
    float m_run = -INFINITY, l_run = 0.f;

    for (int t = 0; t < ntiles; ++t) {
      const int k0 = t * BK;
      __syncthreads();  // previous tile's LDS reads done

      // --- stage K into kappa-permuted slots (fp32->bf16, b64 writes) ---
      #pragma unroll
      for (int i = 0; i < 8; ++i) {
        int row = rbase + 8 * i;
        int o = row & 31;
        int slot = (row >> 5) * 32 + (o & 3) + 4 * ((o >> 3) & 1)
                 + 8 * (2 * (o >> 4) + ((o >> 2) & 1));
        v4bf kb;
        kb[0]=(__bf16)pk[i].x; kb[1]=(__bf16)pk[i].y;
        kb[2]=(__bf16)pk[i].z; kb[3]=(__bf16)pk[i].w;
        *(v4bf*)(&Ks[slot * KP + kd4]) = kb;
      }
      // --- stage V: one d column, 4 granule chunks, swizzled b128 writes ---
      #pragma unroll
      for (int gg = 0; gg < 4; ++gg) {
        v8bf w;
        #pragma unroll
        for (int e = 0; e < 8; ++e) w[e] = (__bf16)pv[gg * 8 + e];
        int g = vgb + gg;
        *(v8bf*)(&Vt[(vd * 8 + (g ^ (vd & 7))) * 8]) = w;
      }
      __syncthreads();

      // --- issue next tile's global loads (overlap with compute); the last
      // iteration of phase A prefetches phase B's tile 0 (same kvbase) ---
      if (t + 1 < ntiles)      prefetch(k0 + BK);
      else if (ph == 0)        prefetch(0);

      if (k0 <= wqb + 31) {
        // --- S^T = K · Q^T : two 32-key chunks ---
        v16f s0, s1;
        #pragma unroll
        for (int e = 0; e < 16; ++e) { s0[e] = 0.f; s1[e] = 0.f; }
        #pragma unroll
        for (int dM = 0; dM < 8; ++dM) {
          v8bf ka = *(const v8bf*)(&Ks[(0 * 32 + l31) * KP + dM * 16 + half * 8]);
          s0 = __builtin_amdgcn_mfma_f32_32x32x16_bf16(ka, qf[dM], s0, 0, 0, 0);
        }
        #pragma unroll
        for (int dM = 0; dM < 8; ++dM) {
          v8bf ka = *(const v8bf*)(&Ks[(1 * 32 + l31) * KP + dM * 16 + half * 8]);
          s1 = __builtin_amdgcn_mfma_f32_32x32x16_bf16(ka, qf[dM], s1, 0, 0, 0);
        }
        // --- causal mask (diagonal region only) ---
        if (k0 + BK > wqb) {
          #pragma unroll
          for (int r = 0; r < 16; ++r) {
            int key = k0 + KOFF(r) + half * 8;
            if (key > qglob)      s0[r] = -INFINITY;
            if (key + 32 > qglob) s1[r] = -INFINITY;
          }
        }
        // --- online softmax (lane owns q=qglob; halves hold disjoint keys) ---
        float m0 = s0[0];
        #pragma unroll
        for (int r = 1; r < 16; ++r) m0 = fmaxf(m0, s0[r]);
        #pragma unroll
        for (int r = 0; r < 16; ++r) m0 = fmaxf(m0, s1[r]);
        m0 = fmaxf(m0, __shfl_xor(m0, 32));
        float mn = fmaxf(m_run, m0);
        float al = __expf(m_run - mn);
        float rs = 0.f;
        #pragma unroll
        for (int r = 0; r < 16; ++r) { float pp = __expf(s0[r] - mn); s0[r] = pp; rs += pp; }
        #pragma unroll
        for (int r = 0; r < 16; ++r) { float pp = __expf(s1[r] - mn); s1[r] = pp; rs += pp; }
        rs += __shfl_xor(rs, 32);
        l_run = l_run * al + rs;
        m_run = mn;
        // --- broadcast alpha to accO row layout via wave-private LDS ---
        if (half == 0) alq[wave * 32 + l31] = al;
        float4 alf[4];
        #pragma unroll
        for (int c = 0; c < 4; ++c)
          alf[c] = *(const float4*)(&alq[wave * 32 + 8 * c + 4 * half]);
        #pragma unroll
        for (int dt = 0; dt < 4; ++dt)
          #pragma unroll
          for (int r = 0; r < 16; ++r)
            accO[dt][r] *= ((const float*)&alf[r >> 2])[r & 3];
        // --- O += P V : A = P (in regs, kappa-aligned), B = Vt chunks ---
        #pragma unroll
        for (int C = 0; C < 2; ++C) {
          #pragma unroll
          for (int cp = 0; cp < 2; ++cp) {
            v8bf pf;
            #pragma unroll
            for (int e = 0; e < 8; ++e)
              pf[e] = (__bf16)(C == 0 ? s0[cp * 8 + e] : s1[cp * 8 + e]);
            int g = (C * 2 + cp) * 2 + half;
            #pragma unroll
            for (int dt = 0; dt < 4; ++dt) {
              int d = dt * 32 + l31;
              v8bf vb = *(const v8bf*)(&Vt[(d * 8 + (g ^ (d & 7))) * 8]);
              accO[dt] = __builtin_amdgcn_mfma_f32_32x32x16_bf16(pf, vb, accO[dt], 0, 0, 0);
            }
          }
        }
      }
    }

    // --- epilogue: O / l, fp32 stores ---
    if (half == 0) alq[wave * 32 + l31] = 1.f / l_run;
    float4 invf[4];
    #pragma unroll
    for (int c = 0; c < 4; ++c)
      invf[c] = *(const float4*)(&alq[wave * 32 + 8 * c + 4 * half]);
    #pragma unroll
    for (int dt = 0; dt < 4; ++dt) {
      #pragma unroll
      for (int r = 0; r < 16; ++r) {
        int qrow = (r & 3) + 8 * (r >> 2) + 4 * half;
        float* op = og + ((size_t)((b * NS + wqb + qrow) * NHQ + h)) * ND;
        op[dt * 32 + l31] = accO[dt][r] * ((const float*)&invf[r >> 2])[r & 3];
      }
    }
  }
}

extern "C" void kernel_launch(void* const* d_in, const int* in_sizes, int n_in,
                              void* d_out, int out_size, void* d_ws, size_t ws_size,
                              hipStream_t stream) {
  const float* q = (const float*)d_in[0];
  const float* k = (const float*)d_in[1];
  const float* v = (const float*)d_in[2];
  float* out = (float*)d_out;
  dim3 grid(NB * NHQ * 4);  // 4 * 32 * 4 = 512 equal-work pair-blocks
  fattn<<<grid, 256, 0, stream>>>(q, k, v, out);
}

// Round 2
// 204.582 us; speedup vs baseline: 1.1143x; 1.1071x over previous
//
#include <hip/hip_runtime.h>
#include <hip/hip_bf16.h>

// Flash-attention (causal, GQA) B=4, S=1024, HQ=32, HK=8, D=128, fp32 io.
// R4: 32x32x16 MFMAs, S^T orientation (D = K·Q^T), kappa-permuted K slots so
// P exits softmax already in PV A-operand layout (no LDS round-trip, no Ps).
// R5: causal load-balance via pair-blocks (p, 7-p): 18 tiles for EVERY block;
// phase B reverses wave->row so each wave is causal-active exactly 17 tiles.
// R6: latency attack. rocprof r1: all pipes <21% busy, ~16.5k cyc/tile vs
// ~1.1k busy; FETCH 208MB (~6x K/V refetch). K/V rows are 4KB-strided ->
// 512 lines/tile served at L3/HBM latency because the 16 blocks sharing a
// (b,hk) stream were scattered over all 8 XCDs. Changes:
//  (1) XCD-grouped mapping: bx&7 = hk -> all 16 sharers on one XCD; K/V
//      becomes L2-resident (4 streams x ~active-window per XCD).
//  (2) LDS double-buffer + ONE __syncthreads per tile (stage writes overlap
//      laggard waves' compute; prefetch still never crosses a barrier).
//  (3) V prefetch as 8x float4 (was 32 scalar dwords); Vt swizzle becomes
//      g^((d>>2)&7) on write AND read (uniform 8 lanes/bank-quad both sides).
//  (4) defer-rescale: skip accO*alpha + broadcast when no lane's max grew
//      (alpha==1 exactly -> numerically identical).
//  (5) s_setprio(1) around MFMA clusters.
//
// Layout facts used (m74/m101-verified): 32x32 C/D: col=lane&31,
// row=(reg&3)+8*(reg>>2)+4*(lane>>5). A: m=lane&31, k=(lane>>5)*8+j.
// B: n=lane&31, k=(lane>>5)*8+j.
// kappa(mu): slot mu holds key 16*(mu_s>>1) + 8*mu_h + (mu_s&1)*4 + mu_r
// (mu = r + 4h + 8s) => P regs [8c..8c+7] are exactly PV A-frag elements.

typedef __bf16 v8bf __attribute__((ext_vector_type(8)));
typedef __bf16 v4bf __attribute__((ext_vector_type(4)));
typedef float  v16f __attribute__((ext_vector_type(16)));

#define NB  4
#define NS  1024
#define NHQ 32
#define NHK 8
#define ND  128
#define BQ  128
#define BK  64
#define KP  136

#define KOFF(r) (16*((r)>>3) + ((((r)>>2)&1)*4) + ((r)&3))

__global__ __launch_bounds__(256, 2)
void fattn(const float* __restrict__ qg, const float* __restrict__ kg,
           const float* __restrict__ vg, float* __restrict__ og)
{
  __shared__ __align__(16) __bf16 Ks[2][BK * KP];   // 2x17408 B, kappa slots
  __shared__ __align__(16) __bf16 Vt[2][ND * BK];   // 2x16384 B, chunk swizzle
  __shared__ __align__(16) float  alq[4 * 32];      // per-wave alpha / inv-l

  const int tid  = threadIdx.x;
  const int lane = tid & 63;
  const int wave = tid >> 6;
  const int half = lane >> 5;
  const int l31  = lane & 31;

  // --- XCD-grouped decode: bx = ((b*16 + p*4 + c) << 3) | hk ---
  const int bx = blockIdx.x;
  const int hk = bx & 7;                 // = XCD id under round-robin dispatch
  const int t6 = bx >> 3;                // 0..63
  const int b  = t6 >> 4;                // batch
  const int m6 = t6 & 15;
  const int p  = m6 >> 2;                // q-tile pair id: tiles (p, 7-p)
  const int h  = hk * 4 + (m6 & 3);      // query head within the hk group

  const float scale = 0.08838834764831845f;  // 1/sqrt(128)
  const size_t kvbase = (size_t)(b * NS) * (NHK * ND) + (size_t)hk * ND;

  // staging assignments
  const int rbase = tid >> 5;            // K: rows rbase + 8i, i=0..7
  const int kd4   = (tid & 31) << 2;     // K: d offset (float4)
  const int vdg   = tid & 31;            // V: d-group, d = 4*vdg + j
  const int vkq   = tid >> 5;            // V: granule (8 keys) index 0..7

  float4 pk[8];
  float4 pvf[8];
  auto prefetch = [&](int kn) {
    #pragma unroll
    for (int i = 0; i < 8; ++i)
      pk[i] = *(const float4*)(kg + kvbase + (size_t)(kn + rbase + 8 * i) * (NHK * ND) + kd4);
    const float* vp = vg + kvbase + (size_t)(kn + vkq * 8) * (NHK * ND) + 4 * vdg;
    #pragma unroll
    for (int kk = 0; kk < 8; ++kk)
      pvf[kk] = *(const float4*)(vp + (size_t)kk * (NHK * ND));
  };

  prefetch(0);
  int cur = 0;

  for (int ph = 0; ph < 2; ++ph) {
    const int qt = ph ? (7 - p) : p;
    const int wv = ph ? (3 - wave) : wave;   // reverse rows in phase B
    const int q0 = qt * BQ;
    const int wqb = q0 + wv * 32;
    const int qglob = wqb + l31;             // this lane's q row
    const int ntiles = 2 * (qt + 1);

    // --- Q fragments (B-operand: n=q=l31, k=d=dM*16+half*8+j), scale folded ---
    v8bf qf[8];
    {
      const float* qp = qg + ((size_t)((b * NS + qglob) * NHQ + h)) * ND + half * 8;
      #pragma unroll
      for (int dM = 0; dM < 8; ++dM) {
        float4 f0 = *(const float4*)(qp + dM * 16);
        float4 f1 = *(const float4*)(qp + dM * 16 + 4);
        v8bf t;
        t[0]=(__bf16)(f0.x*scale); t[1]=(__bf16)(f0.y*scale);
        t[2]=(__bf16)(f0.z*scale); t[3]=(__bf16)(f0.w*scale);
        t[4]=(__bf16)(f1.x*scale); t[5]=(__bf16)(f1.y*scale);
        t[6]=(__bf16)(f1.z*scale); t[7]=(__bf16)(f1.w*scale);
        qf[dM] = t;
      }
    }

    v16f accO[4];
    #pragma unroll
    for (int dt = 0; dt < 4; ++dt)
      #pragma unroll
      for (int e = 0; e < 16; ++e) accO[dt][e] = 0.f;
    float m_run = -INFINITY, l_run = 0.f;

    for (int t = 0; t < ntiles; ++t) {
      const int k0 = t * BK;
      __bf16* ksb = &Ks[cur][0];
      __bf16* vtb = &Vt[cur][0];

      // --- stage K into kappa-permuted slots (fp32->bf16, b64 writes) ---
      #pragma unroll
      for (int i = 0; i < 8; ++i) {
        int row = rbase + 8 * i;
        int o = row & 31;
        int slot = (row >> 5) * 32 + (o & 3) + 4 * ((o >> 3) & 1)
                 + 8 * (2 * (o >> 4) + ((o >> 2) & 1));
        v4bf kb;
        kb[0]=(__bf16)pk[i].x; kb[1]=(__bf16)pk[i].y;
        kb[2]=(__bf16)pk[i].z; kb[3]=(__bf16)pk[i].w;
        *(v4bf*)(&ksb[slot * KP + kd4]) = kb;
      }
      // --- stage V: 4 d-columns x 1 granule each, swizzled b128 writes ---
      #pragma unroll
      for (int j = 0; j < 4; ++j) {
        int d = 4 * vdg + j;
        v8bf w;
        #pragma unroll
        for (int e = 0; e < 8; ++e) w[e] = (__bf16)(((const float*)&pvf[e])[j]);
        *(v8bf*)(&vtb[(d * 8 + (vkq ^ (vdg & 7))) * 8]) = w;   // (d>>2)&7 == vdg&7
      }

      __syncthreads();   // single barrier: buf[cur] full, buf[cur^1] free

      // --- issue next tile's global loads (land during compute) ---
      if (t + 1 < ntiles)      prefetch(k0 + BK);
      else if (ph == 0)        prefetch(0);

      if (k0 <= wqb + 31) {
        const __bf16* ksr = &Ks[cur][0];
        const __bf16* vtr = &Vt[cur][0];
        // --- S^T = K · Q^T : two 32-key chunks ---
        v16f s0, s1;
        #pragma unroll
        for (int e = 0; e < 16; ++e) { s0[e] = 0.f; s1[e] = 0.f; }
        __builtin_amdgcn_s_setprio(1);
        #pragma unroll
        for (int dM = 0; dM < 8; ++dM) {
          v8bf ka = *(const v8bf*)(&ksr[(0 * 32 + l31) * KP + dM * 16 + half * 8]);
          s0 = __builtin_amdgcn_mfma_f32_32x32x16_bf16(ka, qf[dM], s0, 0, 0, 0);
        }
        #pragma unroll
        for (int dM = 0; dM < 8; ++dM) {
          v8bf ka = *(const v8bf*)(&ksr[(1 * 32 + l31) * KP + dM * 16 + half * 8]);
          s1 = __builtin_amdgcn_mfma_f32_32x32x16_bf16(ka, qf[dM], s1, 0, 0, 0);
        }
        __builtin_amdgcn_s_setprio(0);
        // --- causal mask (diagonal region only) ---
        if (k0 + BK > wqb) {
          #pragma unroll
          for (int r = 0; r < 16; ++r) {
            int key = k0 + KOFF(r) + half * 8;
            if (key > qglob)      s0[r] = -INFINITY;
            if (key + 32 > qglob) s1[r] = -INFINITY;
          }
        }
        // --- online softmax (lane owns q=qglob; halves hold disjoint keys) ---
        float m0 = s0[0];
        #pragma unroll
        for (int r = 1; r < 16; ++r) m0 = fmaxf(m0, s0[r]);
        #pragma unroll
        for (int r = 0; r < 16; ++r) m0 = fmaxf(m0, s1[r]);
        m0 = fmaxf(m0, __shfl_xor(m0, 32));
        float mn = fmaxf(m_run, m0);
        float rs = 0.f;
        #pragma unroll
        for (int r = 0; r < 16; ++r) { float pp = __expf(s0[r] - mn); s0[r] = pp; rs += pp; }
        #pragma unroll
        for (int r = 0; r < 16; ++r) { float pp = __expf(s1[r] - mn); s1[r] = pp; rs += pp; }
        rs += __shfl_xor(rs, 32);
        // --- defer-rescale: alpha==1 for every lane -> skip (exact) ---
        if (__any(m0 > m_run)) {
          float al = __expf(m_run - mn);
          if (half == 0) alq[wave * 32 + l31] = al;
          float4 alf[4];
          #pragma unroll
          for (int c = 0; c < 4; ++c)
            alf[c] = *(const float4*)(&alq[wave * 32 + 8 * c + 4 * half]);
          #pragma unroll
          for (int dt = 0; dt < 4; ++dt)
            #pragma unroll
            for (int r = 0; r < 16; ++r)
              accO[dt][r] *= ((const float*)&alf[r >> 2])[r & 3];
          l_run = l_run * al + rs;
        } else {
          l_run += rs;
        }
        m_run = mn;
        // --- O += P V : A = P (in regs, kappa-aligned), B = Vt chunks ---
        __builtin_amdgcn_s_setprio(1);
        #pragma unroll
        for (int C = 0; C < 2; ++C) {
          #pragma unroll
          for (int cp = 0; cp < 2; ++cp) {
            v8bf pf;
            #pragma unroll
            for (int e = 0; e < 8; ++e)
              pf[e] = (__bf16)(C == 0 ? s0[cp * 8 + e] : s1[cp * 8 + e]);
            int g = (C * 2 + cp) * 2 + half;
            #pragma unroll
            for (int dt = 0; dt < 4; ++dt) {
              int d = dt * 32 + l31;
              v8bf vb = *(const v8bf*)(&vtr[(d * 8 + (g ^ ((l31 >> 2) & 7))) * 8]);
              accO[dt] = __builtin_amdgcn_mfma_f32_32x32x16_bf16(pf, vb, accO[dt], 0, 0, 0);
            }
          }
        }
        __builtin_amdgcn_s_setprio(0);
      }
      cur ^= 1;
    }

    // --- epilogue: O / l, fp32 stores ---
    if (half == 0) alq[wave * 32 + l31] = 1.f / l_run;
    float4 invf[4];
    #pragma unroll
    for (int c = 0; c < 4; ++c)
      invf[c] = *(const float4*)(&alq[wave * 32 + 8 * c + 4 * half]);
    #pragma unroll
    for (int dt = 0; dt < 4; ++dt) {
      #pragma unroll
      for (int r = 0; r < 16; ++r) {
        int qrow = (r & 3) + 8 * (r >> 2) + 4 * half;
        float* op = og + ((size_t)((b * NS + wqb + qrow) * NHQ + h)) * ND;
        op[dt * 32 + l31] = accO[dt][r] * ((const float*)&invf[r >> 2])[r & 3];
      }
    }
  }
}

extern "C" void kernel_launch(void* const* d_in, const int* in_sizes, int n_in,
                              void* d_out, int out_size, void* d_ws, size_t ws_size,
                              hipStream_t stream) {
  const float* q = (const float*)d_in[0];
  const float* k = (const float*)d_in[1];
  const float* v = (const float*)d_in[2];
  float* out = (float*)d_out;
  dim3 grid(NB * NHQ * 4);  // 512 equal-work pair-blocks, XCD-grouped
  fattn<<<grid, 256, 0, stream>>>(q, k, v, out);
}

// Round 3
// 190.653 us; speedup vs baseline: 1.1957x; 1.0731x over previous
//
#include <hip/hip_runtime.h>
#include <hip/hip_bf16.h>
#include <stdint.h>

// Flash-attention (causal, GQA) B=4, S=1024, HQ=32, HK=8, D=128, fp32 io.
// R4: 32x32x16 MFMAs, S^T orientation (D = K·Q^T), kappa-permuted K slots so
// P exits softmax already in PV A-operand layout.
// R5: causal load-balance via pair-blocks (p, 7-p): 18 tiles every block.
// R6: XCD-grouped mapping (bx&7 = hk), LDS double-buffer, defer-rescale.
// R7: bf16 pre-pass + global_load_lds DMA staging.
//   rocprof r2: all pipes <23% busy, ~6.9k cyc/tile vs ~2.5k busy. The
//   staging path (16 fp32 VMEM + ~100 conv VALU + 12 ds_write per thread,
//   serial vmcnt->convert->ds_write->barrier chain) and fp32 K/V L2 traffic
//   (128 KB/CU-tile ~ 2.3k cyc floor) dominate. Fix: one-shot prep kernel
//   writes K/V to workspace as bf16 in the EXACT kappa-permuted,
//   XOR-swizzled byte image the LDS tile wants; main kernel stages a tile
//   with 8 global_load_lds dwordx4 per wave (no regs, no conversion, no
//   ds_write). K/V VMEM bytes halve; ~150 instr/thread-tile removed.
//   LDS K swizzle: byte ^= (slot&7)<<4 (T2-style), baked into global layout
//   on the write side (both-sides-or-neither, m104/m231 rule).
//
// Layout facts (m74/m101-verified): 32x32 C/D: col=lane&31,
// row=(reg&3)+8*(reg>>2)+4*(lane>>5). A: m=lane&31, k=(lane>>5)*8+j.
// B: n=lane&31, k=(lane>>5)*8+j.
// kappa(mu): slot mu holds key 16*(mu_s>>1) + 8*mu_h + (mu_s&1)*4 + mu_r
// (mu = r + 4h + 8s) => P regs [8c..8c+7] are exactly PV A-frag elements.

typedef __bf16 v8bf __attribute__((ext_vector_type(8)));
typedef __bf16 v4bf __attribute__((ext_vector_type(4)));
typedef float  v16f __attribute__((ext_vector_type(16)));

#define NB  4
#define NS  1024
#define NHQ 32
#define NHK 8
#define ND  128
#define BQ  128
#define BK  64

#define KOFF(r) (16*((r)>>3) + ((((r)>>2)&1)*4) + ((r)&3))

// key row within tile -> kappa slot (identical to R4-R6 stage formula)
__device__ __forceinline__ int kslot(int row) {
  int o = row & 31;
  return (row >> 5) * 32 + (o & 3) + 4 * ((o >> 3) & 1)
       + 8 * (2 * (o >> 4) + ((o >> 2) & 1));
}

// ---------------- pre-pass: fp32 K/V -> bf16 tiles in LDS byte-image ------
// ws layout: tile tb = (b*8+hk)*16 + t  (t = K-tile index, 64 keys), 32 KB
// per tile: [0,16384) = K image (slot-major 256B rows, byte^=(slot&7)<<4),
// [16384,32768) = V image ((d*8 + (g^((d>>2)&7)))*16 + 2*(key&7)).
__global__ __launch_bounds__(256)
void prep(const float* __restrict__ kg, const float* __restrict__ vg,
          char* __restrict__ ws)
{
  const int tid = threadIdx.x;
  const int blk = blockIdx.x;
  if (blk < 4096) {                 // ---- K: 1M threads, float4 -> 8B write
    int gid = blk * 256 + tid;
    int i  = gid & 31;              // d-quad, d = 4i..4i+3
    int s  = (gid >> 5) & (NS - 1); // key within (b,hk)
    int hk = (gid >> 15) & 7;
    int b  = gid >> 18;
    float4 f = *(const float4*)(kg + ((size_t)((b * NS + s) * NHK + hk)) * ND + 4 * i);
    v4bf kb;
    kb[0]=(__bf16)f.x; kb[1]=(__bf16)f.y; kb[2]=(__bf16)f.z; kb[3]=(__bf16)f.w;
    int t = s >> 6, row = s & 63;
    int slot = kslot(row);
    int byte = (slot * 256 + 8 * i) ^ ((slot & 7) << 4);
    size_t tb = (size_t)((b * 8 + hk) * 16 + t) << 15;
    *(v4bf*)(ws + tb + byte) = kb;
  } else {                          // ---- V: 0.5M threads, 8 gathers -> 16B
    int vid = (blk - 4096) * 256 + tid;
    int d  = vid & 127;
    int g  = (vid >> 7) & 7;        // granule = 8 keys
    int t  = (vid >> 10) & 15;
    int hk = (vid >> 14) & 7;
    int b  = vid >> 17;
    const float* vp = vg + ((size_t)((b * NS + t * 64 + g * 8) * NHK + hk)) * ND + d;
    v8bf w;
    #pragma unroll
    for (int e = 0; e < 8; ++e) w[e] = (__bf16)vp[(size_t)e * (NHK * ND)];
    int byte = (d * 8 + (g ^ ((d >> 2) & 7))) * 16;
    size_t tb = (size_t)((b * 8 + hk) * 16 + t) << 15;
    *(v8bf*)(ws + tb + 16384 + byte) = w;
  }
}

// ---------------- main kernel --------------------------------------------
__global__ __launch_bounds__(256, 2)
void fattn(const float* __restrict__ qg, const char* __restrict__ kvg,
           float* __restrict__ og)
{
  __shared__ __align__(16) char  KV[2][32768];  // [K 16K | V 16K] x dbuf
  __shared__ __align__(16) float alq[4 * 32];   // per-wave alpha / inv-l

  const int tid  = threadIdx.x;
  const int lane = tid & 63;
  const int wave = tid >> 6;
  const int half = lane >> 5;
  const int l31  = lane & 31;

  // XCD-grouped decode: bx = ((b*16 + p*4 + c) << 3) | hk
  const int bx = blockIdx.x;
  const int hk = bx & 7;
  const int t6 = bx >> 3;
  const int b  = t6 >> 4;
  const int m6 = t6 & 15;
  const int p  = m6 >> 2;                // q-tile pair id: tiles (p, 7-p)
  const int h  = hk * 4 + (m6 & 3);

  const float scale = 0.08838834764831845f;  // 1/sqrt(128)
  const int kvtile = (b * 8 + hk) * 16;      // ws tile-id base

  // DMA one 32KB K/V tile: 32 chunks of 1KB; wave w takes chunks 8w..8w+7.
  auto dma = [&](int t_, char* dst) {
    const char* src = kvg + ((size_t)(kvtile + t_) << 15);
    #pragma unroll
    for (int i = 0; i < 8; ++i) {
      int c = wave * 8 + i;
      __builtin_amdgcn_global_load_lds(
        (const __attribute__((address_space(1))) void*)(src + c * 1024 + lane * 16),
        (__attribute__((address_space(3))) void*)(dst + c * 1024),
        16, 0, 0);
    }
  };

  dma(0, KV[0]);
  int cur = 0;

  for (int ph = 0; ph < 2; ++ph) {
    const int qt = ph ? (7 - p) : p;
    const int wv = ph ? (3 - wave) : wave;   // reverse rows in phase B
    const int q0 = qt * BQ;
    const int wqb = q0 + wv * 32;
    const int qglob = wqb + l31;
    const int ntiles = 2 * (qt + 1);

    // Q fragments (B-operand: n=q=l31, k=d=dM*16+half*8+j), scale folded
    v8bf qf[8];
    {
      const float* qp = qg + ((size_t)((b * NS + qglob) * NHQ + h)) * ND + half * 8;
      #pragma unroll
      for (int dM = 0; dM < 8; ++dM) {
        float4 f0 = *(const float4*)(qp + dM * 16);
        float4 f1 = *(const float4*)(qp + dM * 16 + 4);
        v8bf t;
        t[0]=(__bf16)(f0.x*scale); t[1]=(__bf16)(f0.y*scale);
        t[2]=(__bf16)(f0.z*scale); t[3]=(__bf16)(f0.w*scale);
        t[4]=(__bf16)(f1.x*scale); t[5]=(__bf16)(f1.y*scale);
        t[6]=(__bf16)(f1.z*scale); t[7]=(__bf16)(f1.w*scale);
        qf[dM] = t;
      }
    }

    v16f accO[4];
    #pragma unroll
    for (int dt = 0; dt < 4; ++dt)
      #pragma unroll
      for (int e = 0; e < 16; ++e) accO[dt][e] = 0.f;
    float m_run = -INFINITY, l_run = 0.f;

    for (int t = 0; t < ntiles; ++t) {
      const int k0 = t * BK;

      // barrier's implicit vmcnt/lgkm drain: my DMA into KV[cur] landed and
      // every wave finished reading KV[cur^1] (last iter's compute).
      asm volatile("s_waitcnt vmcnt(0)" ::: "memory");
      __syncthreads();

      // issue next tile's DMA into the free buffer (lands during compute)
      if (t + 1 < ntiles)      dma(t + 1, KV[cur ^ 1]);
      else if (ph == 0)        dma(0, KV[cur ^ 1]);

      if (k0 <= wqb + 31) {
        const char* ksr = KV[cur];
        const char* vtr = KV[cur] + 16384;
        // --- S^T = K · Q^T : two 32-key chunks (swizzled b128 reads) ---
        v16f s0, s1;
        #pragma unroll
        for (int e = 0; e < 16; ++e) { s0[e] = 0.f; s1[e] = 0.f; }
        const int kxor = (l31 & 7) << 4;
        __builtin_amdgcn_s_setprio(1);
        #pragma unroll
        for (int dM = 0; dM < 8; ++dM) {
          v8bf ka = *(const v8bf*)(ksr + ((l31 * 256 + dM * 32 + half * 16) ^ kxor));
          s0 = __builtin_amdgcn_mfma_f32_32x32x16_bf16(ka, qf[dM], s0, 0, 0, 0);
        }
        #pragma unroll
        for (int dM = 0; dM < 8; ++dM) {
          v8bf ka = *(const v8bf*)(ksr + (((32 + l31) * 256 + dM * 32 + half * 16) ^ kxor));
          s1 = __builtin_amdgcn_mfma_f32_32x32x16_bf16(ka, qf[dM], s1, 0, 0, 0);
        }
        __builtin_amdgcn_s_setprio(0);
        // --- causal mask (diagonal region only) ---
        if (k0 + BK > wqb) {
          #pragma unroll
          for (int r = 0; r < 16; ++r) {
            int key = k0 + KOFF(r) + half * 8;
            if (key > qglob)      s0[r] = -INFINITY;
            if (key + 32 > qglob) s1[r] = -INFINITY;
          }
        }
        // --- online softmax (lane owns q=qglob; halves hold disjoint keys) ---
        float m0 = s0[0];
        #pragma unroll
        for (int r = 1; r < 16; ++r) m0 = fmaxf(m0, s0[r]);
        #pragma unroll
        for (int r = 0; r < 16; ++r) m0 = fmaxf(m0, s1[r]);
        m0 = fmaxf(m0, __shfl_xor(m0, 32));
        float mn = fmaxf(m_run, m0);
        float rs = 0.f;
        #pragma unroll
        for (int r = 0; r < 16; ++r) { float pp = __expf(s0[r] - mn); s0[r] = pp; rs += pp; }
        #pragma unroll
        for (int r = 0; r < 16; ++r) { float pp = __expf(s1[r] - mn); s1[r] = pp; rs += pp; }
        rs += __shfl_xor(rs, 32);
        // --- defer-rescale: alpha==1 for every lane -> skip (exact) ---
        if (__any(m0 > m_run)) {
          float al = __expf(m_run - mn);
          if (half == 0) alq[wave * 32 + l31] = al;
          float4 alf[4];
          #pragma unroll
          for (int c = 0; c < 4; ++c)
            alf[c] = *(const float4*)(&alq[wave * 32 + 8 * c + 4 * half]);
          #pragma unroll
          for (int dt = 0; dt < 4; ++dt)
            #pragma unroll
            for (int r = 0; r < 16; ++r)
              accO[dt][r] *= ((const float*)&alf[r >> 2])[r & 3];
          l_run = l_run * al + rs;
        } else {
          l_run += rs;
        }
        m_run = mn;
        // --- O += P V : A = P (in regs, kappa-aligned), B = V image ---
        __builtin_amdgcn_s_setprio(1);
        #pragma unroll
        for (int C = 0; C < 2; ++C) {
          #pragma unroll
          for (int cp = 0; cp < 2; ++cp) {
            v8bf pf;
            #pragma unroll
            for (int e = 0; e < 8; ++e)
              pf[e] = (__bf16)(C == 0 ? s0[cp * 8 + e] : s1[cp * 8 + e]);
            int g = (C * 2 + cp) * 2 + half;
            #pragma unroll
            for (int dt = 0; dt < 4; ++dt) {
              int d = dt * 32 + l31;
              v8bf vb = *(const v8bf*)(vtr + (d * 8 + (g ^ ((l31 >> 2) & 7))) * 16);
              accO[dt] = __builtin_amdgcn_mfma_f32_32x32x16_bf16(pf, vb, accO[dt], 0, 0, 0);
            }
          }
        }
        __builtin_amdgcn_s_setprio(0);
      }
      cur ^= 1;
    }

    // --- epilogue: O / l, fp32 stores ---
    if (half == 0) alq[wave * 32 + l31] = 1.f / l_run;
    float4 invf[4];
    #pragma unroll
    for (int c = 0; c < 4; ++c)
      invf[c] = *(const float4*)(&alq[wave * 32 + 8 * c + 4 * half]);
    #pragma unroll
    for (int dt = 0; dt < 4; ++dt) {
      #pragma unroll
      for (int r = 0; r < 16; ++r) {
        int qrow = (r & 3) + 8 * (r >> 2) + 4 * half;
        float* op = og + ((size_t)((b * NS + wqb + qrow) * NHQ + h)) * ND;
        op[dt * 32 + l31] = accO[dt][r] * ((const float*)&invf[r >> 2])[r & 3];
      }
    }
  }
}

extern "C" void kernel_launch(void* const* d_in, const int* in_sizes, int n_in,
                              void* d_out, int out_size, void* d_ws, size_t ws_size,
                              hipStream_t stream) {
  const float* q = (const float*)d_in[0];
  const float* k = (const float*)d_in[1];
  const float* v = (const float*)d_in[2];
  float* out = (float*)d_out;
  char* ws = (char*)d_ws;   // needs 16 MiB: 512 tiles x 32 KB bf16 K/V image
  prep<<<dim3(4096 + 2048), 256, 0, stream>>>(k, v, ws);
  fattn<<<dim3(NB * NHQ * 4), 256, 0, stream>>>(q, ws, out);
}